// Round 13
// baseline (469.618 us; speedup 1.0000x reference)
//
#include <hip/hip_runtime.h>
#include <math.h>

#define NN 10000
#define EE 100000
#define EPE 110000   // edges + self loops
#define CC 200
#define MPAD 10112   // 79 * 128

typedef __attribute__((ext_vector_type(8))) _Float16 f16x8;
typedef __attribute__((ext_vector_type(4))) _Float16 f16x4;
typedef __attribute__((ext_vector_type(4))) unsigned short u16x4;
typedef __attribute__((ext_vector_type(4))) float f32x4;

__device__ __forceinline__ float lrelu(float v) { return v >= 0.f ? v : 0.2f * v; }
__device__ __forceinline__ float gelu_f(float v) { return 0.5f * v * (1.f + erff(v * 0.70710678118654752f)); }

// ---------------- CSR build ----------------

__global__ void build_edges_kernel(const int* __restrict__ ei,
                                   int* __restrict__ src_all, int* __restrict__ dst_all,
                                   int* __restrict__ deg) {
    int e = blockIdx.x * blockDim.x + threadIdx.x;
    if (e >= EPE) return;
    int s, d;
    if (e < EE) { s = ei[e]; d = ei[EE + e]; }
    else        { s = e - EE; d = e - EE; }
    src_all[e] = s;
    dst_all[e] = d;
    atomicAdd(&deg[d], 1);
}

// single-pass scan: 1 block x 1024 threads, 10 elements/thread
__global__ void scan_kernel(const int* __restrict__ deg, int* __restrict__ row_ptr) {
    int tid = threadIdx.x;
    int lane = tid & 63, w = tid >> 6;
    int base = tid * 10;
    int v[10];
    int tot = 0;
#pragma unroll
    for (int j = 0; j < 10; ++j) {
        int idx = base + j;
        v[j] = (idx < NN) ? deg[idx] : 0;
        tot += v[j];
    }
    int inc = tot;
#pragma unroll
    for (int off = 1; off < 64; off <<= 1) {
        int t = __shfl_up(inc, off);
        if (lane >= off) inc += t;
    }
    __shared__ int ws[16];
    if (lane == 63) ws[w] = inc;
    __syncthreads();
    if (w == 0) {
        int s = (lane < 16) ? ws[lane] : 0;
#pragma unroll
        for (int off = 1; off < 16; off <<= 1) {
            int t = __shfl_up(s, off);
            if (lane >= off) s += t;
        }
        if (lane < 16) ws[lane] = s;
    }
    __syncthreads();
    int excl = inc - tot + ((w > 0) ? ws[w - 1] : 0);
    int run = excl;
#pragma unroll
    for (int j = 0; j < 10; ++j) {
        int idx = base + j;
        if (idx < NN) row_ptr[idx] = run;
        run += v[j];
    }
    if (base == NN) row_ptr[NN] = excl;
}

__global__ void scatter_kernel(const int* __restrict__ src_all, const int* __restrict__ dst_all,
                               const int* __restrict__ row_ptr, int* __restrict__ cursor,
                               int* __restrict__ col_src, int* __restrict__ col_eid) {
    int e = blockIdx.x * blockDim.x + threadIdx.x;
    if (e >= EPE) return;
    int d = dst_all[e];
    int pos = row_ptr[d] + atomicAdd(&cursor[d], 1);
    col_src[pos] = src_all[e];
    col_eid[pos] = e;
}

// ---------------- mega prep kernel ----------------
// region 0: zero deg/cursor; region 1: zero Ap pads; region 2: convA layer-0;
// region 3: convB transpose all 5 layers (32x32 LDS tiles)

#define PREP_R0 79
#define PREP_R1 (PREP_R0 + 1614)
#define PREP_R2 (PREP_R1 + 10112)
#define PREP_R3 (PREP_R2 + 2616)

__global__ __launch_bounds__(256) void prep_kernel(const float* __restrict__ X,
                                                   const float* __restrict__ W0,
                                                   const float* __restrict__ W1,
                                                   const float* __restrict__ W2,
                                                   const float* __restrict__ W3,
                                                   const float* __restrict__ W4,
                                                   int* __restrict__ degcur,
                                                   unsigned short* __restrict__ Ap0,
                                                   unsigned short* __restrict__ Ap,
                                                   unsigned short* __restrict__ Bp) {
    __shared__ float tl[32][33];
    int bid = blockIdx.x;
    int tid = threadIdx.x;

    if (bid < PREP_R0) {
        int idx = bid * 256 + tid;
        if (idx < 2 * NN) degcur[idx] = 0;
        return;
    }
    if (bid < PREP_R1) {
        int idx = (bid - PREP_R0) * 256 + tid;
        if (idx < NN * 32) {
            int rw = idx >> 5, c = idx & 31;
            Ap[(size_t)rw * 832 + 800 + c] = 0;
        } else {
            int j = idx - NN * 32;
            if (j < (MPAD - NN) * 832) {
                int rw = j / 832, c = j - rw * 832;
                Ap[(size_t)(NN + rw) * 832 + c] = 0;
            }
        }
        return;
    }
    if (bid < PREP_R2) {
        int idx = (bid - PREP_R1) * 256 + tid;
        int row = idx >> 8, kk = idx & 255;
        float v = 0.f;
        if (row < NN && kk < 200) v = X[(size_t)row * 200 + kk];
        Ap0[idx] = __builtin_bit_cast(unsigned short, (_Float16)v);
        return;
    }
    int t = bid - PREP_R2;
    int l, t0;
    if (t < 224)       { l = 0; t0 = 0; }
    else if (t < 952)  { l = 1; t0 = 224; }
    else if (t < 1680) { l = 2; t0 = 952; }
    else if (t < 2408) { l = 3; t0 = 1680; }
    else               { l = 4; t0 = 2408; }
    const float* W = (l == 0) ? W0 : (l == 1) ? W1 : (l == 2) ? W2 : (l == 3) ? W3 : W4;
    int Fin = (l == 0) ? 200 : 800;
    int HC  = (l == 4) ? 200 : 800;
    int Kp  = (l == 0) ? 256 : 832;
    int ntk = Kp >> 5;
    int tile = t - t0;
    int kt = tile % ntk, nt = tile / ntk;
    int n0 = nt * 32, k0 = kt * 32;
    int tx = tid & 31, ty = tid >> 5;

#pragma unroll
    for (int j = 0; j < 4; ++j) {
        int kk = k0 + ty + j * 8;
        int n  = n0 + tx;
        float v = (kk < Fin && n < HC) ? W[(size_t)kk * HC + n] : 0.f;
        tl[ty + j * 8][tx] = v;
    }
    __syncthreads();
    unsigned short* Bpl = Bp + (size_t)l * (896 * 832);
#pragma unroll
    for (int j = 0; j < 4; ++j) {
        int n  = n0 + ty + j * 8;
        int kk = k0 + tx;
        Bpl[(size_t)n * Kp + kk] =
            __builtin_bit_cast(unsigned short, (_Float16)tl[tx][ty + j * 8]);
    }
}

// ---------------- MFMA GEMM (128x128, single buffer; best measured) ----------------

__global__ __launch_bounds__(256) void gemm_mfma(const unsigned short* __restrict__ A,
                                                 const unsigned short* __restrict__ B,
                                                 unsigned short* __restrict__ C,
                                                 int Kt, int Np, int ncol) {
    __shared__ unsigned short As[8192];   // [128 rows][64 k] swizzled, 16 KB
    __shared__ unsigned short Bs[8192];

    int tid = threadIdx.x;
    int lane = tid & 63, wave = tid >> 6;

    int nwg = gridDim.x;
    int orig = blockIdx.x;
    int q = nwg >> 3, r = nwg & 7;
    int xcd = orig & 7, sidx = orig >> 3;
    int wg = (xcd < r ? xcd * (q + 1) : r * (q + 1) + (xcd - r) * q) + sidx;
    int rowT = wg / ncol, colT = wg - rowT * ncol;
    int row0 = rowT * 128, col0 = colT * 128;
    int wr = wave >> 1, wc = wave & 1;

    size_t gAoff[4], gBoff[4];
    int ldsSeg[4];
#pragma unroll
    for (int i = 0; i < 4; ++i) {
        int seg = wave * 4 + i;            // 0..15
        int chunkIdx = seg * 64 + lane;    // 0..1023
        int rr = chunkIdx >> 3;            // row 0..127
        int c = chunkIdx & 7;
        int cg = c ^ (rr & 7);             // pre-swizzled source chunk
        gAoff[i] = (size_t)(row0 + rr) * Kt + (size_t)cg * 8;
        gBoff[i] = (size_t)(col0 + rr) * Kt + (size_t)cg * 8;
        ldsSeg[i] = seg * 512;
    }

    int rowA[4], rowB[4];
#pragma unroll
    for (int m = 0; m < 4; ++m) {
        rowA[m] = wr * 64 + m * 16 + (lane & 15);
        rowB[m] = wc * 64 + m * 16 + (lane & 15);
    }

    int iaOff[2][4], ibOff[2][4];
#pragma unroll
    for (int kh = 0; kh < 2; ++kh) {
        int cw = kh * 4 + (lane >> 4);
#pragma unroll
        for (int m = 0; m < 4; ++m)
            iaOff[kh][m] = rowA[m] * 64 + ((cw ^ (rowA[m] & 7)) << 3);
#pragma unroll
        for (int n = 0; n < 4; ++n)
            ibOff[kh][n] = rowB[n] * 64 + ((cw ^ (rowB[n] & 7)) << 3);
    }

    f32x4 acc[4][4];
#pragma unroll
    for (int m = 0; m < 4; ++m)
#pragma unroll
        for (int n = 0; n < 4; ++n) acc[m][n] = f32x4{0.f, 0.f, 0.f, 0.f};

    for (int k0 = 0; k0 < Kt; k0 += 64) {
#pragma unroll
        for (int i = 0; i < 4; ++i) {
            __builtin_amdgcn_global_load_lds(
                (const __attribute__((address_space(1))) void*)(A + gAoff[i] + k0),
                (__attribute__((address_space(3))) void*)(&As[ldsSeg[i]]), 16, 0, 0);
            __builtin_amdgcn_global_load_lds(
                (const __attribute__((address_space(1))) void*)(B + gBoff[i] + k0),
                (__attribute__((address_space(3))) void*)(&Bs[ldsSeg[i]]), 16, 0, 0);
        }
        __syncthreads();

#pragma unroll
        for (int kh = 0; kh < 2; ++kh) {
            f16x8 a[4], b[4];
#pragma unroll
            for (int m = 0; m < 4; ++m) a[m] = *(const f16x8*)(&As[iaOff[kh][m]]);
#pragma unroll
            for (int n = 0; n < 4; ++n) b[n] = *(const f16x8*)(&Bs[ibOff[kh][n]]);
#pragma unroll
            for (int m = 0; m < 4; ++m)
#pragma unroll
                for (int n = 0; n < 4; ++n)
                    acc[m][n] = __builtin_amdgcn_mfma_f32_16x16x32_f16(a[m], b[n], acc[m][n], 0, 0, 0);
        }
        __syncthreads();
    }

    int crow = row0 + wr * 64 + ((lane >> 4) << 2);
    int ccol = col0 + wc * 64 + (lane & 15);
#pragma unroll
    for (int m = 0; m < 4; ++m)
#pragma unroll
        for (int j = 0; j < 4; ++j) {
            size_t rb = (size_t)(crow + m * 16 + j) * Np;
#pragma unroll
            for (int n = 0; n < 4; ++n)
                C[rb + ccol + n * 16] =
                    __builtin_bit_cast(unsigned short, (_Float16)acc[m][n][j]);
        }
}

// ---------------- attention scores (vectorized fp16 h) ----------------

__global__ void attn_kernel(const unsigned short* __restrict__ h,
                            const float* __restrict__ a_s, const float* __restrict__ a_d,
                            float* __restrict__ asrc, float* __restrict__ adst,
                            int H, int HCp) {
    int n = blockIdx.x;
    int wave = threadIdx.x >> 6;
    int lane = threadIdx.x & 63;
    float sa = 0.f, da = 0.f;
    int c0 = lane * 4;
    if (c0 < CC) {
        f16x4 hv = *(const f16x4*)(h + (size_t)n * HCp + wave * CC + c0);
        float4 av = *(const float4*)(a_s + wave * CC + c0);
        float4 dv = *(const float4*)(a_d + wave * CC + c0);
        float h0 = (float)hv[0], h1 = (float)hv[1], h2 = (float)hv[2], h3 = (float)hv[3];
        sa = h0 * av.x + h1 * av.y + h2 * av.z + h3 * av.w;
        da = h0 * dv.x + h1 * dv.y + h2 * dv.z + h3 * dv.w;
    }
#pragma unroll
    for (int off = 32; off > 0; off >>= 1) {
        sa += __shfl_down(sa, off);
        da += __shfl_down(da, off);
    }
    if (lane == 0) {
        asrc[n * H + wave] = sa;
        adst[n * H + wave] = da;
    }
}

// ---------------- barrier-free fused softmax + aggregation + bias + gelu ----------------
// one wave per (node, head); weights/src broadcast via __shfl, no LDS, no barriers.
// lane<50 owns 4 channels of this head's 200-ch slice; 2-deep gather prefetch.

__global__ void fused_agg_kernel(const unsigned short* __restrict__ h,
                                 const float* __restrict__ asrc,
                                 const float* __restrict__ adst,
                                 const int* __restrict__ row_ptr,
                                 const int* __restrict__ col_src,
                                 const int* __restrict__ col_eid,
                                 const float* __restrict__ bias,
                                 float* __restrict__ out32,
                                 unsigned short* __restrict__ apn,
                                 float* __restrict__ wout,
                                 int H, int HC, int HCp) {
    int n = blockIdx.x;
    int head = threadIdx.x >> 6;
    int lane = threadIdx.x & 63;
    int beg = row_ptr[n], end = row_ptr[n + 1];

    float ad = adst[n * H + head];

    // pass 1: online m/den, lane-strided, butterfly merge (all lanes get result)
    float m = -1e30f, den = 0.f;
    for (int e = beg + lane; e < end; e += 64) {
        float v = lrelu(asrc[col_src[e] * H + head] + ad);
        if (v > m) { den = den * expf(m - v) + 1.f; m = v; }
        else den += expf(v - m);
    }
#pragma unroll
    for (int off = 1; off < 64; off <<= 1) {
        float m2 = __shfl_xor(m, off);
        float d2 = __shfl_xor(den, off);
        float M = fmaxf(m, m2);
        den = den * expf(m - M) + d2 * expf(m2 - M);
        m = M;
    }
    float inv = 1.f / den;

    int c4 = lane * 4;                     // channel offset within head slice
    bool own = (c4 < CC);
    const unsigned short* hbase = h + (size_t)head * CC + c4;
    float a0 = 0.f, a1 = 0.f, a2 = 0.f, a3 = 0.f;

    for (int c0 = beg; c0 < end; c0 += 64) {
        int cnt = min(64, end - c0);
        int s = 0; float wv = 0.f;
        if (lane < cnt) {
            int e = c0 + lane;
            s = col_src[e];
            float v = lrelu(asrc[s * H + head] + ad);
            wv = expf(v - m) * inv;
            if (wout) wout[(size_t)col_eid[e] * H + head] = wv;
        }
        // 2-deep prefetch; shuffles uniform across wave
        int sj0 = __shfl(s, 0);
        int sj1 = __shfl(s, (cnt > 1) ? 1 : 0);
        f16x4 hva = {}, hvb = {};
        if (own) {
            hva = *(const f16x4*)(hbase + (size_t)sj0 * HCp);
            if (cnt > 1) hvb = *(const f16x4*)(hbase + (size_t)sj1 * HCp);
        }
        for (int j = 0; j < cnt; ++j) {
            int sj2 = __shfl(s, (j + 2 < cnt) ? j + 2 : 0);
            float wj = __shfl(wv, j);
            f16x4 hvc = {};
            if (own && j + 2 < cnt) hvc = *(const f16x4*)(hbase + (size_t)sj2 * HCp);
            a0 += wj * (float)hva[0];
            a1 += wj * (float)hva[1];
            a2 += wj * (float)hva[2];
            a3 += wj * (float)hva[3];
            hva = hvb; hvb = hvc;
        }
    }

    if (own) {
        int ch = head * CC + c4;
        float4 bv = *(const float4*)(bias + ch);
        float g0 = gelu_f(a0 + bv.x), g1 = gelu_f(a1 + bv.y);
        float g2 = gelu_f(a2 + bv.z), g3 = gelu_f(a3 + bv.w);
        if (out32) {
            *(float4*)(out32 + (size_t)n * HC + ch) = float4{g0, g1, g2, g3};
        } else {
            *(u16x4*)(apn + (size_t)n * 832 + ch) = u16x4{
                __builtin_bit_cast(unsigned short, (_Float16)g0),
                __builtin_bit_cast(unsigned short, (_Float16)g1),
                __builtin_bit_cast(unsigned short, (_Float16)g2),
                __builtin_bit_cast(unsigned short, (_Float16)g3)};
        }
    }
}

// ---------------- host ----------------

extern "C" void kernel_launch(void* const* d_in, const int* in_sizes, int n_in,
                              void* d_out, int out_size, void* d_ws, size_t ws_size,
                              hipStream_t stream) {
    const float* X = (const float*)d_in[0];
    const int* ei = (const int*)d_in[1];

    char* ws = (char*)d_ws;
    size_t off = 0;
    auto alloc = [&](size_t bytes) { void* p = ws + off; off += (bytes + 255) & ~(size_t)255; return p; };

    unsigned short* Ap0 = (unsigned short*)alloc((size_t)MPAD * 256 * 2);       // 5.2 MB
    unsigned short* Ap  = (unsigned short*)alloc((size_t)MPAD * 832 * 2);       // 16.8 MB
    unsigned short* Bp  = (unsigned short*)alloc((size_t)5 * 896 * 832 * 2);    // 7.5 MB
    unsigned short* hbuf= (unsigned short*)alloc((size_t)MPAD * 896 * 2);       // 18.1 MB
    float* attn_all = (float*)alloc((size_t)5 * 2 * NN * 4 * 4);                // 1.6 MB
    int* src_all  = (int*)alloc((size_t)EPE * 4);
    int* dst_all  = (int*)alloc((size_t)EPE * 4);
    int* col_src  = (int*)alloc((size_t)EPE * 4);
    int* col_eid  = (int*)alloc((size_t)EPE * 4);
    int* row_ptr  = (int*)alloc((size_t)(NN + 1) * 4);
    int* degcur   = (int*)alloc((size_t)2 * NN * 4);
    int* deg = degcur, * cursor = degcur + NN;

    prep_kernel<<<PREP_R3, 256, 0, stream>>>(X,
        (const float*)d_in[2], (const float*)d_in[6], (const float*)d_in[10],
        (const float*)d_in[14], (const float*)d_in[18],
        degcur, Ap0, Ap, Bp);

    int eb = (EPE + 255) / 256;
    build_edges_kernel<<<eb, 256, 0, stream>>>(ei, src_all, dst_all, deg);
    scan_kernel<<<1, 1024, 0, stream>>>(deg, row_ptr);
    scatter_kernel<<<eb, 256, 0, stream>>>(src_all, dst_all, row_ptr, cursor, col_src, col_eid);

    for (int i = 0; i < 5; ++i) {
        int H   = (i == 4) ? 1 : 4;
        int HC  = H * CC;
        int Kp  = (i == 0) ? 256 : 832;
        int Np  = (i == 4) ? 256 : 896;
        int ncol = Np / 128;
        const unsigned short* Acur = (i == 0) ? Ap0 : Ap;
        const unsigned short* Bpl = Bp + (size_t)i * (896 * 832);
        const float* as_ = (const float*)d_in[3 + 4 * i];
        const float* ad_ = (const float*)d_in[4 + 4 * i];
        const float* b_  = (const float*)d_in[5 + 4 * i];
        float* asrc_l = attn_all + (size_t)i * 2 * NN * 4;
        float* adst_l = asrc_l + NN * 4;

        gemm_mfma<<<ncol * (MPAD / 128), 256, 0, stream>>>(Acur, Bpl, hbuf, Kp, Np, ncol);

        attn_kernel<<<NN, H * 64, 0, stream>>>(hbuf, as_, ad_, asrc_l, adst_l, H, Np);

        float* out32 = (i == 4) ? (float*)d_out : nullptr;
        unsigned short* apn = (i == 4) ? nullptr : Ap;
        float* wout = (i == 4) ? (float*)d_out + (size_t)NN * CC : nullptr;
        fused_agg_kernel<<<NN, H * 64, 0, stream>>>(hbuf, asrc_l, adst_l, row_ptr, col_src,
                                                    col_eid, b_, out32, apn, wout, H, HC, Np);
    }
}